// Round 12
// baseline (310.345 us; speedup 1.0000x reference)
//
#include <hip/hip_runtime.h>
#include <hip/hip_bf16.h>
#include <cstdint>
#include <cstddef>

#define T_TOK 4096
#define DIM   1024
#define NE    8
#define DFF   2048
#define NSLOT 8192   // T_TOK * TOP_K

typedef __bf16 bf16x8 __attribute__((ext_vector_type(8)));
typedef float  f32x4  __attribute__((ext_vector_type(4)));
typedef unsigned short u16;
typedef unsigned short u16x8 __attribute__((ext_vector_type(8)));

__device__ __forceinline__ u16 f2bf(float f) {
  union { float f; uint32_t u; } v; v.f = f;
  uint32_t r = (v.u + 0x7FFFu + ((v.u >> 16) & 1u)) >> 16;
  return (u16)r;
}

typedef const __attribute__((address_space(1))) uint32_t* gas_ptr;
typedef __attribute__((address_space(3))) uint32_t* las_ptr;
__device__ __forceinline__ void gl_lds16(const void* g, void* l) {
  __builtin_amdgcn_global_load_lds((gas_ptr)g, (las_ptr)l, 16, 0, 0);
}

#define VM5 asm volatile("s_waitcnt vmcnt(5)" ::: "memory")
#define VM3 asm volatile("s_waitcnt vmcnt(3)" ::: "memory")
#define VM2 asm volatile("s_waitcnt vmcnt(2)" ::: "memory")
#define VM0 asm volatile("s_waitcnt vmcnt(0)" ::: "memory")
#define LG0 asm volatile("s_waitcnt lgkmcnt(0)" ::: "memory")

// =====================================================================================
// pre_kernel: gate only (fp32 scores/softmax/top-2, no atomics; emits xb)
// =====================================================================================
__global__ __launch_bounds__(256) void pre_kernel(
    const float* __restrict__ x, const float* __restrict__ gw,
    u16* __restrict__ xb, int* __restrict__ idx, float* __restrict__ wts) {
  __shared__ float sgw[NE * DIM];
  int b = blockIdx.x, tid = threadIdx.x;
  const float4* gw4 = (const float4*)gw;
  float4* sgw4 = (float4*)sgw;
#pragma unroll
  for (int i = 0; i < 8; ++i) sgw4[tid + i * 256] = gw4[tid + i * 256];
  __syncthreads();
  int wave = tid >> 6, lane = tid & 63;
  int t = b * 4 + wave;
  float xv[16];
#pragma unroll
  for (int j = 0; j < 16; ++j) xv[j] = x[(size_t)t * DIM + lane + j * 64];
#pragma unroll
  for (int j = 0; j < 16; ++j) xb[(size_t)t * DIM + lane + j * 64] = f2bf(xv[j]);
  float s[NE];
#pragma unroll
  for (int e = 0; e < NE; ++e) {
    float a = 0.f;
#pragma unroll
    for (int j = 0; j < 16; ++j) a += xv[j] * sgw[e * DIM + lane + j * 64];
    s[e] = a;
  }
#pragma unroll
  for (int off = 32; off > 0; off >>= 1) {
#pragma unroll
    for (int e = 0; e < NE; ++e) s[e] += __shfl_xor(s[e], off, 64);
  }
  if (lane == 0) {
    float m = s[0];
#pragma unroll
    for (int e = 1; e < NE; ++e) m = fmaxf(m, s[e]);
    float p[NE];
#pragma unroll
    for (int e = 0; e < NE; ++e) p[e] = __expf(s[e] - m);
    int i0 = 0;
#pragma unroll
    for (int e = 1; e < NE; ++e) if (s[e] > s[i0]) i0 = e;
    int i1 = (i0 == 0) ? 1 : 0;
#pragma unroll
    for (int e = 0; e < NE; ++e) if (e != i1 && e != i0 && s[e] > s[i1]) i1 = e;
    float p0 = p[i0], p1 = p[i1], inv = 1.f / (p0 + p1);
    idx[2 * t] = i0; idx[2 * t + 1] = i1;
    wts[2 * t] = p0 * inv; wts[2 * t + 1] = p1 * inv;
  }
}

// =====================================================================================
// scan_scatter: single block. Ballot-histogram -> scan -> ballot-rank scatter.
// =====================================================================================
__global__ __launch_bounds__(1024) void scan_scatter_kernel(
    const int* __restrict__ idx, const float* __restrict__ wts, int* __restrict__ offs,
    int* __restrict__ perm, float* __restrict__ wt_slot, int* __restrict__ slot_of) {
  __shared__ int shist[NE];
  __shared__ int soff[NE + 1];
  __shared__ int scur[NE];
  int tid = threadIdx.x, lane = tid & 63;
  if (tid < NE) shist[tid] = 0;
  __syncthreads();
  int eloc[8];
#pragma unroll
  for (int it = 0; it < 8; ++it) {
    int s = it * 1024 + tid;
    int e = idx[s];
    eloc[it] = e;
#pragma unroll
    for (int E = 0; E < NE; ++E) {
      unsigned long long m = __ballot(e == E);
      int leader = m ? (int)__builtin_ctzll(m) : -1;
      if (lane == leader) atomicAdd(&shist[E], (int)__popcll(m));
    }
  }
  __syncthreads();
  if (tid == 0) {
    int a = 0;
    for (int e = 0; e < NE; ++e) { soff[e] = a; scur[e] = a; a += shist[e]; }
    soff[NE] = a;
  }
  __syncthreads();
  if (tid < NE + 1) offs[tid] = soff[tid];
#pragma unroll
  for (int it = 0; it < 8; ++it) {
    int s = it * 1024 + tid;
    int e = eloc[it];
    int pos = 0;
#pragma unroll
    for (int E = 0; E < NE; ++E) {
      unsigned long long m = __ballot(e == E);
      int leader = m ? (int)__builtin_ctzll(m) : 0;
      int base = 0;
      if (m && lane == leader) base = atomicAdd(&scur[E], (int)__popcll(m));
      base = __shfl(base, leader, 64);
      if (e == E) pos = base + (int)__popcll(m & ((1ull << lane) - 1ull));
    }
    perm[pos] = s >> 1;
    wt_slot[pos] = wts[s];
    slot_of[s] = pos;
  }
}

// =====================================================================================
// ffn1: h = silu(X*W1^T).*(X*W3^T)  BM=128, BN=128, BK=32, 512 thr (8 waves, 2x4)
// W1/W3 read as FP32 and converted during reg-staging (no pre-conversion pass).
// A via gl_lds from xb (bf16). 3-deep circular LDS 72 KiB -> 2 blocks/CU.
// Per tile: issue {B(t+2)x4 fp32->regs, A(t+2) gl_lds}; cvt+ds_write B(t+1);
// vmcnt(5)+lgkmcnt(0) before flip barrier. Blocks >= 1136 convert w2 (for ffn2).
// LDS elems: A buf b @ b*4096, B1 @ 12288+b*4096, B3 @ 24576+b*4096
// =====================================================================================
__global__ __launch_bounds__(512, 4) void ffn1_kernel(
    const u16* __restrict__ xb, const float* __restrict__ w1, const float* __restrict__ w3,
    const int* __restrict__ offs, const int* __restrict__ perm, u16* __restrict__ h,
    const float* __restrict__ w2, u16* __restrict__ w2b) {
  int bid = blockIdx.x, tid = threadIdx.x;
  if (bid >= 1136) {
    // ---- w2 fp32 -> bf16 (512 filler blocks, fills ffn1's tail round) ----
    const long n = (long)NE * DIM * DFF;
    long cb = bid - 1136;
    long stride = 512L * 512 * 8;
    for (long i = (cb * 512 + tid) * 8; i < n; i += stride) {
      float4 a = *(const float4*)(w2 + i);
      float4 c = *(const float4*)(w2 + i + 4);
      u16x8 r;
      r[0] = f2bf(a.x); r[1] = f2bf(a.y); r[2] = f2bf(a.z); r[3] = f2bf(a.w);
      r[4] = f2bf(c.x); r[5] = f2bf(c.y); r[6] = f2bf(c.z); r[7] = f2bf(c.w);
      *(u16x8*)(w2b + i) = r;
    }
    return;
  }
  __shared__ u16 smem[36864];
  int wave = tid >> 6, lane = tid & 63;
  int wr = wave >> 2, wc = wave & 3;
  int lrow = lane & 15, lq = lane >> 4;
  int nid = (bid & 7) * 142 + (bid >> 3);   // 1136 = 8 * 142, bijective
  int bx = nid / 71;    // f-tile 0..15
  int by = nid % 71;    // m-block
  int e = -1, mblk = 0;
  {
    int acc = 0;
    for (int i = 0; i < NE; ++i) {
      int c = offs[i + 1] - offs[i];
      int nb = (c + 127) >> 7;
      if (by < acc + nb) { e = i; mblk = by - acc; break; }
      acc += nb;
    }
  }
  if (e < 0) return;
  int seg = offs[e], cnt = offs[e + 1] - seg;
  int fBase = bx * 128;

  int srow = tid >> 2, spos = tid & 3;
  int sch = spos ^ ((srow >> 1) & 3);
  const u16* gA;
  {
    int r = mblk * 128 + srow; if (r > cnt - 1) r = cnt - 1;
    gA = xb + (size_t)perm[seg + r] * DIM + sch * 8;
  }
  size_t wb = (size_t)e * DFF * DIM;
  const float* gW1 = w1 + wb + (size_t)(fBase + srow) * DIM + sch * 8;
  const float* gW3 = w3 + wb + (size_t)(fBase + srow) * DIM + sch * 8;

  int p8 = (lq ^ ((lrow >> 1) & 3)) * 8;
  int aoff[4], boff[2];
#pragma unroll
  for (int m = 0; m < 4; ++m) aoff[m] = (wr * 64 + m * 16 + lrow) * 32 + p8;
#pragma unroll
  for (int n = 0; n < 2; ++n) boff[n] = (wc * 32 + n * 16 + lrow) * 32 + p8;

  f32x4 acc1[4][2], acc3[4][2];
#pragma unroll
  for (int i = 0; i < 4; ++i)
#pragma unroll
    for (int j = 0; j < 2; ++j) {
      acc1[i][j] = (f32x4){0.f, 0.f, 0.f, 0.f};
      acc3[i][j] = (f32x4){0.f, 0.f, 0.f, 0.f};
    }

  float4 r1a, r1b, r3a, r3b;   // B prefetch regs (one tile in flight)

#define LOADB(kt)                                                            \
  do {                                                                       \
    int kb = (kt) * 32;                                                      \
    r1a = *(const float4*)(gW1 + kb); r1b = *(const float4*)(gW1 + kb + 4);  \
    r3a = *(const float4*)(gW3 + kb); r3b = *(const float4*)(gW3 + kb + 4);  \
  } while (0)

#define STAGE_A1(kt)                                                         \
  gl_lds16(gA + (kt) * 32, &smem[((kt) % 3) * 4096 + wave * 512])

#define CVTWRITE(b)                                                          \
  do {                                                                       \
    bf16x8 c1, c3;                                                           \
    c1[0] = (__bf16)r1a.x; c1[1] = (__bf16)r1a.y; c1[2] = (__bf16)r1a.z;     \
    c1[3] = (__bf16)r1a.w; c1[4] = (__bf16)r1b.x; c1[5] = (__bf16)r1b.y;     \
    c1[6] = (__bf16)r1b.z; c1[7] = (__bf16)r1b.w;                            \
    c3[0] = (__bf16)r3a.x; c3[1] = (__bf16)r3a.y; c3[2] = (__bf16)r3a.z;     \
    c3[3] = (__bf16)r3a.w; c3[4] = (__bf16)r3b.x; c3[5] = (__bf16)r3b.y;     \
    c3[6] = (__bf16)r3b.z; c3[7] = (__bf16)r3b.w;                            \
    *(bf16x8*)&smem[12288 + (b) * 4096 + tid * 8] = c1;                      \
    *(bf16x8*)&smem[24576 + (b) * 4096 + tid * 8] = c3;                      \
  } while (0)

  // prologue: B0 regs + A0; consume B0 -> buf0; B1 regs + A1; wait A0; barrier
  LOADB(0); STAGE_A1(0);
  CVTWRITE(0);                 // compiler auto-waits the B0 loads
  LOADB(1); STAGE_A1(1);
  VM5; LG0;
  __builtin_amdgcn_s_barrier();

#define F1_TILE(T, MODE)                                                     \
  do {                                                                       \
    int buf = (T) % 3;                                                       \
    const u16* lA = &smem[buf * 4096];                                       \
    const u16* lB1 = &smem[12288 + buf * 4096];                              \
    const u16* lB3 = &smem[24576 + buf * 4096];                              \
    bf16x8 a[4], b1[2], b3[2];                                               \
    _Pragma("unroll") for (int m = 0; m < 4; ++m)                            \
        a[m] = *(const bf16x8*)&lA[aoff[m]];                                 \
    _Pragma("unroll") for (int n = 0; n < 2; ++n) {                          \
      b1[n] = *(const bf16x8*)&lB1[boff[n]];                                 \
      b3[n] = *(const bf16x8*)&lB3[boff[n]];                                 \
    }                                                                        \
    if (MODE) CVTWRITE(((T) + 1) % 3);                                       \
    if (MODE == 2) { LOADB((T) + 2); STAGE_A1((T) + 2); }                    \
    __builtin_amdgcn_s_setprio(1);                                           \
    _Pragma("unroll") for (int m = 0; m < 4; ++m)                            \
        _Pragma("unroll") for (int n = 0; n < 2; ++n) {                      \
      acc1[m][n] = __builtin_amdgcn_mfma_f32_16x16x32_bf16(a[m], b1[n], acc1[m][n], 0, 0, 0); \
      acc3[m][n] = __builtin_amdgcn_mfma_f32_16x16x32_bf16(a[m], b3[n], acc3[m][n], 0, 0, 0); \
    }                                                                        \
    __builtin_amdgcn_s_setprio(0);                                           \
    if (MODE == 2) { VM5; }                                                  \
    else if (MODE == 1) { VM0; }                                             \
    if (MODE) { LG0; __builtin_amdgcn_s_barrier(); }                         \
  } while (0)

  const int NT = DIM / 32;  // 32
  for (int t = 0; t < NT - 2; ++t) F1_TILE(t, 2);
  F1_TILE(NT - 2, 1);
  F1_TILE(NT - 1, 0);
#undef F1_TILE
#undef CVTWRITE
#undef STAGE_A1
#undef LOADB

  // epilogue: silu(c1)*c3 -> h
#pragma unroll
  for (int mi = 0; mi < 4; ++mi) {
#pragma unroll
    for (int jj = 0; jj < 4; ++jj) {
      int lr = mblk * 128 + wr * 64 + mi * 16 + lq * 4 + jj;
      if (lr < cnt) {
        size_t slot = (size_t)(seg + lr);
#pragma unroll
        for (int ni = 0; ni < 2; ++ni) {
          float c1v = acc1[mi][ni][jj], c3v = acc3[mi][ni][jj];
          float sv = c1v / (1.f + __expf(-c1v));
          int f = fBase + wc * 32 + ni * 16 + lrow;
          h[slot * DFF + f] = f2bf(sv * c3v);
        }
      }
    }
  }
}

// =====================================================================================
// ffn2: y = wt * (H * W2^T)   BM=128, BN=128, BK=32, 512 thr, 3-deep 48 KiB,
// 3 blocks/CU (launch_bounds 512,6). vmcnt(2) steady.  [R11-proven, unchanged]
// =====================================================================================
__global__ __launch_bounds__(512, 6) void ffn2_kernel(
    const u16* __restrict__ h, const u16* __restrict__ w2b,
    const int* __restrict__ offs, const float* __restrict__ wt_slot,
    float* __restrict__ y) {
  __shared__ u16 smem[24576];
  int tid = threadIdx.x, wave = tid >> 6, lane = tid & 63;
  int wr = wave >> 2, wc = wave & 3;
  int lrow = lane & 15, lq = lane >> 4;
  int bid = blockIdx.x;                 // 568 = 8 * 71
  int nid = (bid & 7) * 71 + (bid >> 3);
  int bx = nid / 71;                    // d-tile 0..7
  int by = nid % 71;
  int e = -1, mblk = 0;
  {
    int acc = 0;
    for (int i = 0; i < NE; ++i) {
      int c = offs[i + 1] - offs[i];
      int nb = (c + 127) >> 7;
      if (by < acc + nb) { e = i; mblk = by - acc; break; }
      acc += nb;
    }
  }
  if (e < 0) return;
  int seg = offs[e], cnt = offs[e + 1] - seg;
  int dBase = bx * 128;

  int srow = tid >> 2, spos = tid & 3;
  int sch = spos ^ ((srow >> 1) & 3);
  const u16* gA;
  {
    int r = mblk * 128 + srow; if (r > cnt - 1) r = cnt - 1;
    gA = h + (size_t)(seg + r) * DFF + sch * 8;
  }
  const u16* gB = w2b + (size_t)e * DIM * DFF + (size_t)(dBase + srow) * DFF + sch * 8;

  int p8 = (lq ^ ((lrow >> 1) & 3)) * 8;
  int aoff[4], boff[2];
#pragma unroll
  for (int m = 0; m < 4; ++m) aoff[m] = (wr * 64 + m * 16 + lrow) * 32 + p8;
#pragma unroll
  for (int n = 0; n < 2; ++n) boff[n] = (wc * 32 + n * 16 + lrow) * 32 + p8;

  f32x4 acc[4][2];
#pragma unroll
  for (int i = 0; i < 4; ++i)
#pragma unroll
    for (int j = 0; j < 2; ++j) acc[i][j] = (f32x4){0.f, 0.f, 0.f, 0.f};

#define STAGE_F2(kt)                                                         \
  do {                                                                       \
    int kb = (kt) * 32, b = (kt) % 3;                                        \
    gl_lds16(gA + kb, &smem[b * 4096 + wave * 512]);                         \
    gl_lds16(gB + kb, &smem[12288 + b * 4096 + wave * 512]);                 \
  } while (0)

#define F2_TILE(T, STG, VM, BAR)                                             \
  do {                                                                       \
    int buf = (T) % 3;                                                       \
    const u16* lA = &smem[buf * 4096];                                       \
    const u16* lB = &smem[12288 + buf * 4096];                               \
    bf16x8 a[4], b[2];                                                       \
    _Pragma("unroll") for (int m = 0; m < 4; ++m)                            \
        a[m] = *(const bf16x8*)&lA[aoff[m]];                                 \
    _Pragma("unroll") for (int n = 0; n < 2; ++n)                            \
        b[n] = *(const bf16x8*)&lB[boff[n]];                                 \
    if (STG) STAGE_F2((T) + 2);                                              \
    __builtin_amdgcn_s_setprio(1);                                           \
    _Pragma("unroll") for (int m = 0; m < 4; ++m)                            \
        _Pragma("unroll") for (int n = 0; n < 2; ++n)                        \
            acc[m][n] = __builtin_amdgcn_mfma_f32_16x16x32_bf16(a[m], b[n], acc[m][n], 0, 0, 0); \
    __builtin_amdgcn_s_setprio(0);                                           \
    VM;                                                                      \
    if (BAR) __builtin_amdgcn_s_barrier();                                   \
  } while (0)

  STAGE_F2(0); STAGE_F2(1);
  VM2;
  __builtin_amdgcn_s_barrier();

  const int NT = DFF / 32;  // 64
  for (int t = 0; t < NT - 2; ++t) F2_TILE(t, true, VM2, true);
  F2_TILE(NT - 2, false, VM0, true);
  F2_TILE(NT - 1, false, (void)0, false);
#undef F2_TILE
#undef STAGE_F2

#pragma unroll
  for (int mi = 0; mi < 4; ++mi) {
#pragma unroll
    for (int jj = 0; jj < 4; ++jj) {
      int lr = mblk * 128 + wr * 64 + mi * 16 + lq * 4 + jj;
      if (lr < cnt) {
        size_t slot = (size_t)(seg + lr);
        float wt = wt_slot[slot];
#pragma unroll
        for (int ni = 0; ni < 2; ++ni) {
          int d = dBase + wc * 32 + ni * 16 + lrow;
          y[slot * DIM + d] = wt * acc[mi][ni][jj];
        }
      }
    }
  }
}

// ---------------- combine: out[t] = y[slot0] + y[slot1] ----------------
__global__ __launch_bounds__(256) void combine_kernel(const float* __restrict__ y,
                                                      const int* __restrict__ slot_of,
                                                      float* __restrict__ out) {
  int t = blockIdx.x, dv = threadIdx.x;
  int s0 = slot_of[2 * t], s1 = slot_of[2 * t + 1];
  const float4* y4 = (const float4*)y;
  float4 a = y4[(size_t)s0 * 256 + dv];
  float4 b = y4[(size_t)s1 * 256 + dv];
  float4 r; r.x = a.x + b.x; r.y = a.y + b.y; r.z = a.z + b.z; r.w = a.w + b.w;
  ((float4*)out)[(size_t)t * 256 + dv] = r;
}

extern "C" void kernel_launch(void* const* d_in, const int* in_sizes, int n_in,
                              void* d_out, int out_size, void* d_ws, size_t ws_size,
                              hipStream_t stream) {
  const float* x  = (const float*)d_in[0];
  const float* gw = (const float*)d_in[1];
  const float* w1 = (const float*)d_in[2];
  const float* w2 = (const float*)d_in[3];
  const float* w3 = (const float*)d_in[4];
  float* out = (float*)d_out;

  char* ws = (char*)d_ws;
  size_t o = 0;
  u16* xb  = (u16*)(ws + o); o += (size_t)T_TOK * DIM * 2;
  u16* w2b = (u16*)(ws + o); o += (size_t)NE * DIM * DFF * 2;
  u16* h   = (u16*)(ws + o); o += (size_t)NSLOT * DFF * 2;
  float* y = (float*)(ws + o); o += (size_t)NSLOT * DIM * 4;
  int* idx      = (int*)(ws + o); o += NSLOT * 4;
  float* wts    = (float*)(ws + o); o += NSLOT * 4;
  int* slot_of  = (int*)(ws + o); o += NSLOT * 4;
  int* perm     = (int*)(ws + o); o += NSLOT * 4;
  float* wt_slot= (float*)(ws + o); o += NSLOT * 4;
  int* offs     = (int*)(ws + o); o += 16 * 4;
  if (o > ws_size) return;

  pre_kernel<<<1024, 256, 0, stream>>>(x, gw, xb, idx, wts);
  scan_scatter_kernel<<<1, 1024, 0, stream>>>(idx, wts, offs, perm, wt_slot, slot_of);
  ffn1_kernel<<<1648, 512, 0, stream>>>(xb, w1, w3, offs, perm, h, w2, w2b);
  ffn2_kernel<<<568, 512, 0, stream>>>(h, w2b, offs, wt_slot, y);
  combine_kernel<<<T_TOK, 256, 0, stream>>>(y, slot_of, out);
}

// Round 13
// 236.282 us; speedup vs baseline: 1.3135x; 1.3135x over previous
//
#include <hip/hip_runtime.h>
#include <hip/hip_bf16.h>
#include <cstdint>
#include <cstddef>

#define T_TOK 4096
#define DIM   1024
#define NE    8
#define DFF   2048
#define NSLOT 8192   // T_TOK * TOP_K

typedef __bf16 bf16x8 __attribute__((ext_vector_type(8)));
typedef float  f32x4  __attribute__((ext_vector_type(4)));
typedef unsigned short u16;
typedef unsigned short u16x8 __attribute__((ext_vector_type(8)));

__device__ __forceinline__ u16 f2bf(float f) {
  union { float f; uint32_t u; } v; v.f = f;
  uint32_t r = (v.u + 0x7FFFu + ((v.u >> 16) & 1u)) >> 16;
  return (u16)r;
}
__device__ __forceinline__ float bf2f(u16 b) {
  union { uint32_t u; float f; } v; v.u = ((uint32_t)b) << 16; return v.f;
}

typedef const __attribute__((address_space(1))) uint32_t* gas_ptr;
typedef __attribute__((address_space(3))) uint32_t* las_ptr;
__device__ __forceinline__ void gl_lds16(const void* g, void* l) {
  __builtin_amdgcn_global_load_lds((gas_ptr)g, (las_ptr)l, 16, 0, 0);
}

#define VM3 asm volatile("s_waitcnt vmcnt(3)" ::: "memory")
#define VM2 asm volatile("s_waitcnt vmcnt(2)" ::: "memory")
#define VM0 asm volatile("s_waitcnt vmcnt(0)" ::: "memory")
#define VMN ((void)0)

// =====================================================================================
// pre_kernel: blocks 0..1023 = gate (fp32 scores/softmax/top-2, no atomics; emits xb)
//             blocks 1024..3071 = fp32->bf16 conversion of w1,w3 (grid-stride)
// =====================================================================================
__global__ __launch_bounds__(256) void pre_kernel(
    const float* __restrict__ x, const float* __restrict__ gw,
    const float* __restrict__ w1, const float* __restrict__ w3,
    u16* __restrict__ xb, u16* __restrict__ w1b, u16* __restrict__ w3b,
    int* __restrict__ idx, float* __restrict__ wts) {
  __shared__ float sgw[NE * DIM];
  int b = blockIdx.x, tid = threadIdx.x;
  if (b < 1024) {
    const float4* gw4 = (const float4*)gw;
    float4* sgw4 = (float4*)sgw;
#pragma unroll
    for (int i = 0; i < 8; ++i) sgw4[tid + i * 256] = gw4[tid + i * 256];
    __syncthreads();
    int wave = tid >> 6, lane = tid & 63;
    int t = b * 4 + wave;
    float xv[16];
#pragma unroll
    for (int j = 0; j < 16; ++j) xv[j] = x[(size_t)t * DIM + lane + j * 64];
#pragma unroll
    for (int j = 0; j < 16; ++j) xb[(size_t)t * DIM + lane + j * 64] = f2bf(xv[j]);
    float s[NE];
#pragma unroll
    for (int e = 0; e < NE; ++e) {
      float a = 0.f;
#pragma unroll
      for (int j = 0; j < 16; ++j) a += xv[j] * sgw[e * DIM + lane + j * 64];
      s[e] = a;
    }
#pragma unroll
    for (int off = 32; off > 0; off >>= 1) {
#pragma unroll
      for (int e = 0; e < NE; ++e) s[e] += __shfl_xor(s[e], off, 64);
    }
    if (lane == 0) {
      float m = s[0];
#pragma unroll
      for (int e = 1; e < NE; ++e) m = fmaxf(m, s[e]);
      float p[NE];
#pragma unroll
      for (int e = 0; e < NE; ++e) p[e] = __expf(s[e] - m);
      int i0 = 0;
#pragma unroll
      for (int e = 1; e < NE; ++e) if (s[e] > s[i0]) i0 = e;
      int i1 = (i0 == 0) ? 1 : 0;
#pragma unroll
      for (int e = 0; e < NE; ++e) if (e != i1 && e != i0 && s[e] > s[i1]) i1 = e;
      float p0 = p[i0], p1 = p[i1], inv = 1.f / (p0 + p1);
      idx[2 * t] = i0; idx[2 * t + 1] = i1;
      wts[2 * t] = p0 * inv; wts[2 * t + 1] = p1 * inv;
    }
  } else {
    const long n = (long)NE * DFF * DIM;
    long bid = b - 1024;
    long stride = 2048L * 256 * 8;
    for (long i = (bid * 256 + tid) * 8; i < 2 * n; i += stride) {
      const float* s; u16* d; long off;
      if (i < n) { s = w1; d = w1b; off = i; }
      else       { s = w3; d = w3b; off = i - n; }
      float4 a = *(const float4*)(s + off);
      float4 c = *(const float4*)(s + off + 4);
      u16x8 r;
      r[0] = f2bf(a.x); r[1] = f2bf(a.y); r[2] = f2bf(a.z); r[3] = f2bf(a.w);
      r[4] = f2bf(c.x); r[5] = f2bf(c.y); r[6] = f2bf(c.z); r[7] = f2bf(c.w);
      *(u16x8*)(d + off) = r;
    }
  }
}

// =====================================================================================
// scan_scatter: single block. Ballot-histogram -> scan -> ballot-rank scatter.
// =====================================================================================
__global__ __launch_bounds__(1024) void scan_scatter_kernel(
    const int* __restrict__ idx, const float* __restrict__ wts, int* __restrict__ offs,
    int* __restrict__ perm, float* __restrict__ wt_slot, int* __restrict__ slot_of) {
  __shared__ int shist[NE];
  __shared__ int soff[NE + 1];
  __shared__ int scur[NE];
  int tid = threadIdx.x, lane = tid & 63;
  if (tid < NE) shist[tid] = 0;
  __syncthreads();
  int eloc[8];
#pragma unroll
  for (int it = 0; it < 8; ++it) {
    int s = it * 1024 + tid;
    int e = idx[s];
    eloc[it] = e;
#pragma unroll
    for (int E = 0; E < NE; ++E) {
      unsigned long long m = __ballot(e == E);
      int leader = m ? (int)__builtin_ctzll(m) : -1;
      if (lane == leader) atomicAdd(&shist[E], (int)__popcll(m));
    }
  }
  __syncthreads();
  if (tid == 0) {
    int a = 0;
    for (int e = 0; e < NE; ++e) { soff[e] = a; scur[e] = a; a += shist[e]; }
    soff[NE] = a;
  }
  __syncthreads();
  if (tid < NE + 1) offs[tid] = soff[tid];
#pragma unroll
  for (int it = 0; it < 8; ++it) {
    int s = it * 1024 + tid;
    int e = eloc[it];
    int pos = 0;
#pragma unroll
    for (int E = 0; E < NE; ++E) {
      unsigned long long m = __ballot(e == E);
      int leader = m ? (int)__builtin_ctzll(m) : 0;
      int base = 0;
      if (m && lane == leader) base = atomicAdd(&scur[E], (int)__popcll(m));
      base = __shfl(base, leader, 64);
      if (e == E) pos = base + (int)__popcll(m & ((1ull << lane) - 1ull));
    }
    perm[pos] = s >> 1;
    wt_slot[pos] = wts[s];
    slot_of[s] = pos;
  }
}

// =====================================================================================
// ffn1: h = silu(X*W1^T).*(X*W3^T)  BM=128, BN=128, BK=32, 512 thr (8 waves, 2x4)
// 3-deep circular LDS 72 KiB -> 2 blocks/CU; counted vmcnt(3).  [R8/R11-proven]
// Blocks >= 1136 (512 of them) convert w2 fp32->bf16 in the tail round.
// =====================================================================================
__global__ __launch_bounds__(512, 4) void ffn1_kernel(
    const u16* __restrict__ xb, const u16* __restrict__ w1b, const u16* __restrict__ w3b,
    const int* __restrict__ offs, const int* __restrict__ perm, u16* __restrict__ h,
    const float* __restrict__ w2, u16* __restrict__ w2b) {
  int bid = blockIdx.x, tid = threadIdx.x;
  if (bid >= 1136) {
    const long n = (long)NE * DIM * DFF;
    long cb = bid - 1136;
    long stride = 512L * 512 * 8;
    for (long i = (cb * 512 + tid) * 8; i < n; i += stride) {
      float4 a = *(const float4*)(w2 + i);
      float4 c = *(const float4*)(w2 + i + 4);
      u16x8 r;
      r[0] = f2bf(a.x); r[1] = f2bf(a.y); r[2] = f2bf(a.z); r[3] = f2bf(a.w);
      r[4] = f2bf(c.x); r[5] = f2bf(c.y); r[6] = f2bf(c.z); r[7] = f2bf(c.w);
      *(u16x8*)(w2b + i) = r;
    }
    return;
  }
  __shared__ u16 smem[36864];
  int wave = tid >> 6, lane = tid & 63;
  int wr = wave >> 2, wc = wave & 3;
  int lrow = lane & 15, lq = lane >> 4;
  int nid = (bid & 7) * 142 + (bid >> 3);   // 1136 = 8 * 142, bijective
  int bx = nid / 71;    // f-tile 0..15
  int by = nid % 71;    // m-block
  int e = -1, mblk = 0;
  {
    int acc = 0;
    for (int i = 0; i < NE; ++i) {
      int c = offs[i + 1] - offs[i];
      int nb = (c + 127) >> 7;
      if (by < acc + nb) { e = i; mblk = by - acc; break; }
      acc += nb;
    }
  }
  if (e < 0) return;
  int seg = offs[e], cnt = offs[e + 1] - seg;
  int fBase = bx * 128;

  int srow = tid >> 2, spos = tid & 3;
  int sch = spos ^ ((srow >> 1) & 3);
  const u16* gA;
  {
    int r = mblk * 128 + srow; if (r > cnt - 1) r = cnt - 1;
    gA = xb + (size_t)perm[seg + r] * DIM + sch * 8;
  }
  size_t wb = (size_t)e * DFF * DIM;
  const u16* gB1 = w1b + wb + (size_t)(fBase + srow) * DIM + sch * 8;
  const u16* gB3 = w3b + wb + (size_t)(fBase + srow) * DIM + sch * 8;

  int p8 = (lq ^ ((lrow >> 1) & 3)) * 8;
  int aoff[4], boff[2];
#pragma unroll
  for (int m = 0; m < 4; ++m) aoff[m] = (wr * 64 + m * 16 + lrow) * 32 + p8;
#pragma unroll
  for (int n = 0; n < 2; ++n) boff[n] = (wc * 32 + n * 16 + lrow) * 32 + p8;

  f32x4 acc1[4][2], acc3[4][2];
#pragma unroll
  for (int i = 0; i < 4; ++i)
#pragma unroll
    for (int j = 0; j < 2; ++j) {
      acc1[i][j] = (f32x4){0.f, 0.f, 0.f, 0.f};
      acc3[i][j] = (f32x4){0.f, 0.f, 0.f, 0.f};
    }

#define STAGE_F1(kt)                                                         \
  do {                                                                       \
    int kb = (kt) * 32, b = (kt) % 3;                                        \
    gl_lds16(gA + kb, &smem[b * 4096 + wave * 512]);                         \
    gl_lds16(gB1 + kb, &smem[12288 + b * 4096 + wave * 512]);                \
    gl_lds16(gB3 + kb, &smem[24576 + b * 4096 + wave * 512]);                \
  } while (0)

#define F1_TILE(T, STG, VM, BAR)                                             \
  do {                                                                       \
    int buf = (T) % 3;                                                       \
    const u16* lA = &smem[buf * 4096];                                       \
    const u16* lB1 = &smem[12288 + buf * 4096];                              \
    const u16* lB3 = &smem[24576 + buf * 4096];                              \
    bf16x8 a[4], b1[2], b3[2];                                               \
    _Pragma("unroll") for (int m = 0; m < 4; ++m)                            \
        a[m] = *(const bf16x8*)&lA[aoff[m]];                                 \
    _Pragma("unroll") for (int n = 0; n < 2; ++n) {                          \
      b1[n] = *(const bf16x8*)&lB1[boff[n]];                                 \
      b3[n] = *(const bf16x8*)&lB3[boff[n]];                                 \
    }                                                                        \
    if (STG) STAGE_F1((T) + 2);                                              \
    __builtin_amdgcn_s_setprio(1);                                           \
    _Pragma("unroll") for (int m = 0; m < 4; ++m)                            \
        _Pragma("unroll") for (int n = 0; n < 2; ++n) {                      \
      acc1[m][n] = __builtin_amdgcn_mfma_f32_16x16x32_bf16(a[m], b1[n], acc1[m][n], 0, 0, 0); \
      acc3[m][n] = __builtin_amdgcn_mfma_f32_16x16x32_bf16(a[m], b3[n], acc3[m][n], 0, 0, 0); \
    }                                                                        \
    __builtin_amdgcn_s_setprio(0);                                           \
    VM;                                                                      \
    if (BAR) __builtin_amdgcn_s_barrier();                                   \
  } while (0)

  STAGE_F1(0); STAGE_F1(1);
  VM3;
  __builtin_amdgcn_s_barrier();

  const int NT = DIM / 32;  // 32
  for (int t = 0; t < NT - 2; ++t) F1_TILE(t, true, VM3, true);
  F1_TILE(NT - 2, false, VM0, true);
  F1_TILE(NT - 1, false, VMN, false);
#undef F1_TILE
#undef STAGE_F1

#pragma unroll
  for (int mi = 0; mi < 4; ++mi) {
#pragma unroll
    for (int jj = 0; jj < 4; ++jj) {
      int lr = mblk * 128 + wr * 64 + mi * 16 + lq * 4 + jj;
      if (lr < cnt) {
        size_t slot = (size_t)(seg + lr);
#pragma unroll
        for (int ni = 0; ni < 2; ++ni) {
          float c1v = acc1[mi][ni][jj], c3v = acc3[mi][ni][jj];
          float sv = c1v / (1.f + __expf(-c1v));
          int f = fBase + wc * 32 + ni * 16 + lrow;
          h[slot * DFF + f] = f2bf(sv * c3v);
        }
      }
    }
  }
}

// =====================================================================================
// ffn2: y(bf16) = wt * (H * W2^T)   BM=128, BN=128, BK=32, 512 thr, 3-deep 48 KiB,
// 3 blocks/CU (launch_bounds 512,6). vmcnt(2) steady.  [R11-proven; y now bf16]
// =====================================================================================
__global__ __launch_bounds__(512, 6) void ffn2_kernel(
    const u16* __restrict__ h, const u16* __restrict__ w2b,
    const int* __restrict__ offs, const float* __restrict__ wt_slot,
    u16* __restrict__ y) {
  __shared__ u16 smem[24576];
  int tid = threadIdx.x, wave = tid >> 6, lane = tid & 63;
  int wr = wave >> 2, wc = wave & 3;
  int lrow = lane & 15, lq = lane >> 4;
  int bid = blockIdx.x;                 // 568 = 8 * 71
  int nid = (bid & 7) * 71 + (bid >> 3);
  int bx = nid / 71;                    // d-tile 0..7
  int by = nid % 71;
  int e = -1, mblk = 0;
  {
    int acc = 0;
    for (int i = 0; i < NE; ++i) {
      int c = offs[i + 1] - offs[i];
      int nb = (c + 127) >> 7;
      if (by < acc + nb) { e = i; mblk = by - acc; break; }
      acc += nb;
    }
  }
  if (e < 0) return;
  int seg = offs[e], cnt = offs[e + 1] - seg;
  int dBase = bx * 128;

  int srow = tid >> 2, spos = tid & 3;
  int sch = spos ^ ((srow >> 1) & 3);
  const u16* gA;
  {
    int r = mblk * 128 + srow; if (r > cnt - 1) r = cnt - 1;
    gA = h + (size_t)(seg + r) * DFF + sch * 8;
  }
  const u16* gB = w2b + (size_t)e * DIM * DFF + (size_t)(dBase + srow) * DFF + sch * 8;

  int p8 = (lq ^ ((lrow >> 1) & 3)) * 8;
  int aoff[4], boff[2];
#pragma unroll
  for (int m = 0; m < 4; ++m) aoff[m] = (wr * 64 + m * 16 + lrow) * 32 + p8;
#pragma unroll
  for (int n = 0; n < 2; ++n) boff[n] = (wc * 32 + n * 16 + lrow) * 32 + p8;

  f32x4 acc[4][2];
#pragma unroll
  for (int i = 0; i < 4; ++i)
#pragma unroll
    for (int j = 0; j < 2; ++j) acc[i][j] = (f32x4){0.f, 0.f, 0.f, 0.f};

#define STAGE_F2(kt)                                                         \
  do {                                                                       \
    int kb = (kt) * 32, b = (kt) % 3;                                        \
    gl_lds16(gA + kb, &smem[b * 4096 + wave * 512]);                         \
    gl_lds16(gB + kb, &smem[12288 + b * 4096 + wave * 512]);                 \
  } while (0)

#define F2_TILE(T, STG, VM, BAR)                                             \
  do {                                                                       \
    int buf = (T) % 3;                                                       \
    const u16* lA = &smem[buf * 4096];                                       \
    const u16* lB = &smem[12288 + buf * 4096];                               \
    bf16x8 a[4], b[2];                                                       \
    _Pragma("unroll") for (int m = 0; m < 4; ++m)                            \
        a[m] = *(const bf16x8*)&lA[aoff[m]];                                 \
    _Pragma("unroll") for (int n = 0; n < 2; ++n)                            \
        b[n] = *(const bf16x8*)&lB[boff[n]];                                 \
    if (STG) STAGE_F2((T) + 2);                                              \
    __builtin_amdgcn_s_setprio(1);                                           \
    _Pragma("unroll") for (int m = 0; m < 4; ++m)                            \
        _Pragma("unroll") for (int n = 0; n < 2; ++n)                        \
            acc[m][n] = __builtin_amdgcn_mfma_f32_16x16x32_bf16(a[m], b[n], acc[m][n], 0, 0, 0); \
    __builtin_amdgcn_s_setprio(0);                                           \
    VM;                                                                      \
    if (BAR) __builtin_amdgcn_s_barrier();                                   \
  } while (0)

  STAGE_F2(0); STAGE_F2(1);
  VM2;
  __builtin_amdgcn_s_barrier();

  const int NT = DFF / 32;  // 64
  for (int t = 0; t < NT - 2; ++t) F2_TILE(t, true, VM2, true);
  F2_TILE(NT - 2, false, VM0, true);
  F2_TILE(NT - 1, false, VMN, false);
#undef F2_TILE
#undef STAGE_F2

#pragma unroll
  for (int mi = 0; mi < 4; ++mi) {
#pragma unroll
    for (int jj = 0; jj < 4; ++jj) {
      int lr = mblk * 128 + wr * 64 + mi * 16 + lq * 4 + jj;
      if (lr < cnt) {
        size_t slot = (size_t)(seg + lr);
        float wt = wt_slot[slot];
#pragma unroll
        for (int ni = 0; ni < 2; ++ni) {
          int d = dBase + wc * 32 + ni * 16 + lrow;
          y[slot * DIM + d] = f2bf(wt * acc[mi][ni][jj]);
        }
      }
    }
  }
}

// ---------------- combine: out[t] = y[slot0] + y[slot1]  (y bf16, out fp32) ----------
__global__ __launch_bounds__(256) void combine_kernel(const u16* __restrict__ y,
                                                      const int* __restrict__ slot_of,
                                                      float* __restrict__ out) {
  int t = blockIdx.x * 2 + (threadIdx.x >> 7);
  int dv = (threadIdx.x & 127) * 8;   // 8 elems/thread
  int s0 = slot_of[2 * t], s1 = slot_of[2 * t + 1];
  u16x8 a = *(const u16x8*)(y + (size_t)s0 * DIM + dv);
  u16x8 b = *(const u16x8*)(y + (size_t)s1 * DIM + dv);
  float4 r0, r1;
  r0.x = bf2f(a[0]) + bf2f(b[0]); r0.y = bf2f(a[1]) + bf2f(b[1]);
  r0.z = bf2f(a[2]) + bf2f(b[2]); r0.w = bf2f(a[3]) + bf2f(b[3]);
  r1.x = bf2f(a[4]) + bf2f(b[4]); r1.y = bf2f(a[5]) + bf2f(b[5]);
  r1.z = bf2f(a[6]) + bf2f(b[6]); r1.w = bf2f(a[7]) + bf2f(b[7]);
  float* o = out + (size_t)t * DIM + dv;
  *(float4*)o = r0;
  *(float4*)(o + 4) = r1;
}

extern "C" void kernel_launch(void* const* d_in, const int* in_sizes, int n_in,
                              void* d_out, int out_size, void* d_ws, size_t ws_size,
                              hipStream_t stream) {
  const float* x  = (const float*)d_in[0];
  const float* gw = (const float*)d_in[1];
  const float* w1 = (const float*)d_in[2];
  const float* w2 = (const float*)d_in[3];
  const float* w3 = (const float*)d_in[4];
  float* out = (float*)d_out;

  char* ws = (char*)d_ws;
  size_t o = 0;
  u16* xb  = (u16*)(ws + o); o += (size_t)T_TOK * DIM * 2;
  u16* w1b = (u16*)(ws + o); o += (size_t)NE * DFF * DIM * 2;
  u16* w3b = (u16*)(ws + o); o += (size_t)NE * DFF * DIM * 2;
  u16* w2b = (u16*)(ws + o); o += (size_t)NE * DIM * DFF * 2;
  u16* h   = (u16*)(ws + o); o += (size_t)NSLOT * DFF * 2;
  u16* y   = (u16*)(ws + o); o += (size_t)NSLOT * DIM * 2;
  int* idx      = (int*)(ws + o); o += NSLOT * 4;
  float* wts    = (float*)(ws + o); o += NSLOT * 4;
  int* slot_of  = (int*)(ws + o); o += NSLOT * 4;
  int* perm     = (int*)(ws + o); o += NSLOT * 4;
  float* wt_slot= (float*)(ws + o); o += NSLOT * 4;
  int* offs     = (int*)(ws + o); o += 16 * 4;
  if (o > ws_size) return;

  pre_kernel<<<3072, 256, 0, stream>>>(x, gw, w1, w3, xb, w1b, w3b, idx, wts);
  scan_scatter_kernel<<<1, 1024, 0, stream>>>(idx, wts, offs, perm, wt_slot, slot_of);
  ffn1_kernel<<<1648, 512, 0, stream>>>(xb, w1b, w3b, offs, perm, h, w2, w2b);
  ffn2_kernel<<<568, 512, 0, stream>>>(h, w2b, offs, wt_slot, y);
  combine_kernel<<<T_TOK / 2, 256, 0, stream>>>(y, slot_of, out);
}